// Round 12
// baseline (516.782 us; speedup 1.0000x reference)
//
#include <hip/hip_runtime.h>

typedef __attribute__((ext_vector_type(8))) __bf16 bfrag;
typedef __attribute__((ext_vector_type(16))) float f32x16;
typedef unsigned short ushort_t;

__device__ __forceinline__ unsigned short f2bf(float f) {
    union { unsigned int u; float f; } c; c.f = f;
    unsigned int u = c.u;
    return (unsigned short)((u + 0x7FFFu + ((u >> 16) & 1u)) >> 16);
}
__device__ __forceinline__ float2 bfp(unsigned int u) {
    union { unsigned int u; float f; } lo, hi;
    lo.u = u << 16; hi.u = u & 0xFFFF0000u;
    return make_float2(lo.f, hi.f);
}
__device__ __forceinline__ unsigned int pk2(float a, float b) {
    return ((unsigned)f2bf(b) << 16) | f2bf(a);
}

// ---------------- workspace layout (bytes) ----------------
// feat  bf16 [4][320][640][32]   at 0          (52,428,800)
// costs bf16 [4][256][256][128]  at 52428800   (67,108,864)
// x1    bf16 [4][256][256][64]   at 119537664  (33,554,432)
// x2    bf16 [4][256][256][32]   at 153092096  (16,777,216)
// wbf   bf16 packed fusion       at 170917888  (442,368)
// wb1   bf16 packed reg1         at 171360256  (110,592)
// wt2   f32  [kpos][32]          at 171470848  (3,456)
// zp    zero page (64 B)         at 171474304  (64)

// pack conv3d weights (OIDHW fp32) into MFMA B-fragment order, bf16.
// layout: [p = c*3+kd][f = tap*4+ks][wn][lane][8]
template<int CI, int CO>
__device__ __forceinline__ void pack_w_elem(const float* __restrict__ w,
                                            ushort_t* __restrict__ dst, int o) {
    constexpr int WN = CO / 32;
    const int j = o & 7;
    const int lane = (o >> 3) & 63;
    int r = o >> 9;
    const int wn = r % WN; r /= WN;
    const int f = r % 36;  const int p = r / 36;
    const int tap = f >> 2, ks = f & 3;
    const int c = p / 3, kd = p % 3;
    const int co = wn * 32 + (lane & 31);
    const int ci = c * 64 + ks * 16 + (lane >> 5) * 8 + j;
    const int ky = tap / 3, kx = tap % 3;
    dst[o] = f2bf(w[(((size_t)(co * CI + ci) * 3 + kd) * 3 + ky) * 3 + kx]);
}

// single merged weight-prep kernel: fusion pack (864 blocks), reg1 pack
// (216 blocks), reg2 transpose + zero-page (4 blocks). Saves 2 launch gaps.
__global__ void omni_prep(const float* __restrict__ w_fusion,
                          const float* __restrict__ w_reg1,
                          const float* __restrict__ w_reg2,
                          ushort_t* __restrict__ wbf, ushort_t* __restrict__ wb1,
                          float* __restrict__ wt2, float* __restrict__ zp) {
    const int b = blockIdx.x;
    const int tid = threadIdx.x;
    if (b < 864) {
        pack_w_elem<128, 64>(w_fusion, wbf, b * 256 + tid);      // n = 221184 exact
    } else if (b < 1080) {
        pack_w_elem<64, 32>(w_reg1, wb1, (b - 864) * 256 + tid); // n = 55296 exact
    } else {
        const int i = (b - 1080) * 256 + tid;                    // 0..1023
        if (i >= 864) {
            if (i - 864 < 16) zp[i - 864] = 0.f;
            return;
        }
        const int ci = i % 32;
        const int kpos = i / 32;
        wt2[i] = w_reg2[ci * 27 + kpos];
    }
}

// conv2d stride2 pad1 + relu; input NCHW [3,640,1280]; out bf16 channels-last
// [cam][320][640][32]. NOTE (R10 lesson): the LDS-tiled variant (stage input
// window + weights both in LDS, fully unrolled 864-term FMA) ballooned to
// 156 VGPR / 11% occupancy / 235us. This simple 27-scalar-load form compiles
// lean (low VGPR, latency hidden by occupancy) and is the proven config.
__global__ __launch_bounds__(256) void omni_feat_conv(
        const float* __restrict__ c0, const float* __restrict__ c1,
        const float* __restrict__ c2, const float* __restrict__ c3,
        const float* __restrict__ w, ushort_t* __restrict__ feat) {
    __shared__ float wl[864];
    int tid = threadIdx.x;
    for (int i = tid; i < 864; i += 256) wl[i] = w[i];
    __syncthreads();
    int gid = blockIdx.x * 256 + tid;               // 4*320*640
    int ox = gid % 640;
    int t = gid / 640;
    int oy = t % 320;
    int cam = t / 320;
    const float* src = (cam == 0) ? c0 : (cam == 1) ? c1 : (cam == 2) ? c2 : c3;
    float acc[32];
#pragma unroll
    for (int i = 0; i < 32; i++) acc[i] = 0.f;
    for (int ky = 0; ky < 3; ky++) {
        int iy = oy * 2 - 1 + ky;
        if (iy < 0 || iy >= 640) continue;
        for (int kx = 0; kx < 3; kx++) {
            int ix = ox * 2 - 1 + kx;
            if (ix < 0 || ix >= 1280) continue;
#pragma unroll
            for (int ci = 0; ci < 3; ci++) {
                float v = src[(ci * 640 + iy) * 1280 + ix];
#pragma unroll
                for (int co = 0; co < 32; co++)
                    acc[co] += v * wl[((co * 3 + ci) * 3 + ky) * 3 + kx];
            }
        }
    }
    uint4* d4 = (uint4*)(feat + (size_t)gid * 32);
#pragma unroll
    for (int q = 0; q < 4; q++) {
        uint4 v;
        v.x = pk2(fmaxf(acc[8*q+0],0.f), fmaxf(acc[8*q+1],0.f));
        v.y = pk2(fmaxf(acc[8*q+2],0.f), fmaxf(acc[8*q+3],0.f));
        v.z = pk2(fmaxf(acc[8*q+4],0.f), fmaxf(acc[8*q+5],0.f));
        v.w = pk2(fmaxf(acc[8*q+6],0.f), fmaxf(acc[8*q+7],0.f));
        d4[q] = v;
    }
}

// Tiled fused grid_sample + antialiased resize — R4-proven configuration.
// L2-miss-gather-throughput bound; empirical best operating point:
// 16x8 tile, 5 blocks/CU, branchy taps (44 VGPR, no spill), XCD-chunked
// swizzle. R5 branchless: 194us; R6/R7 tap-batching: scratch spill
// (WRITE 221 MB); R8 16x4/8-blk high-TLP: 233us, BW 3.5->2.95 TB/s
// (extra concurrency hurts locality). Do not re-attempt those.
#define NXP 42
#define NYP 12
#define NPOS (NXP * NYP)   // 504
__global__ __launch_bounds__(256, 5) void omni_warp_resize(
        const ushort_t* __restrict__ feat, const float* __restrict__ grids,
        ushort_t* __restrict__ costs) {
    __shared__ uint4 smp4[4 * NPOS];   // 32,256 B -> 5 blocks/CU
    const int tid = threadIdx.x;
    const int bid0 = blockIdx.x;
    const int bid = (bid0 & 7) * 1024 + (bid0 >> 3);   // bijective: XCD k <- chunk k
    const int tx  = bid & 15;
    const int ty  = (bid >> 4) & 31;
    const int d   = (bid >> 9) & 3;
    const int cam = bid >> 11;
    const int x0 = tx * 16, y0 = ty * 8;
    const int jx_base = 40 * tx - 1;
    const int jy_base = 10 * ty - 1;
    const float* gbase = grids + ((size_t)(cam * 4 + d) * 320) * 640 * 2;
    const ushort_t* fbase = feat + (size_t)cam * 320 * 640 * 32;

    for (int i = tid; i < NPOS; i += 256) {
        const int jy = jy_base + i / NXP;
        const int jx = jx_base + i % NXP;
        float acc[32];
#pragma unroll
        for (int c = 0; c < 32; c++) acc[c] = 0.f;
        if ((unsigned)jy < 320u && (unsigned)jx < 640u) {
            const float gx = gbase[((size_t)jy * 640 + jx) * 2];
            const float gy = gbase[((size_t)jy * 640 + jx) * 2 + 1];
            const float fx = (gx + 1.f) * 320.f - 0.5f;
            const float fy = (gy + 1.f) * 160.f - 0.5f;
            const float x0f = floorf(fx), y0f = floorf(fy);
            const float ax = fx - x0f, ay = fy - y0f;
            const int sx0 = (int)x0f, sy0 = (int)y0f;
            const float tw[4] = {(1.f-ax)*(1.f-ay), ax*(1.f-ay), (1.f-ax)*ay, ax*ay};
            const int xs4[4] = {sx0, sx0+1, sx0, sx0+1};
            const int ys4[4] = {sy0, sy0, sy0+1, sy0+1};
#pragma unroll
            for (int tc = 0; tc < 4; tc++) {
                const int xi = xs4[tc], yi = ys4[tc];
                if (xi < 0 || xi >= 640 || yi < 0 || yi >= 320) continue;
                const float wt = tw[tc];
                const uint4* f4 = (const uint4*)(fbase + ((size_t)yi * 640 + xi) * 32);
#pragma unroll
                for (int q = 0; q < 4; q++) {
                    uint4 v = f4[q];
                    float2 p0 = bfp(v.x), p1 = bfp(v.y), p2 = bfp(v.z), p3 = bfp(v.w);
                    acc[8*q+0] += wt * p0.x; acc[8*q+1] += wt * p0.y;
                    acc[8*q+2] += wt * p1.x; acc[8*q+3] += wt * p1.y;
                    acc[8*q+4] += wt * p2.x; acc[8*q+5] += wt * p2.y;
                    acc[8*q+6] += wt * p3.x; acc[8*q+7] += wt * p3.y;
                }
            }
        }
#pragma unroll
        for (int q = 0; q < 4; q++) {
            uint4 v;
            v.x = pk2(acc[8*q+0], acc[8*q+1]);
            v.y = pk2(acc[8*q+2], acc[8*q+3]);
            v.z = pk2(acc[8*q+4], acc[8*q+5]);
            v.w = pk2(acc[8*q+6], acc[8*q+7]);
            smp4[q * NPOS + i] = v;
        }
    }
    __syncthreads();

    const int half = tid >> 7;
    const int p = tid & 127;
    const int x = x0 + (p & 15);
    const int y = y0 + (p >> 4);

    const float sy = 1.25f * y + 0.125f;
    const int jy0 = (int)ceilf(sy - 1.25f);
    float wy[3]; float sumy = 0.f;
#pragma unroll
    for (int t = 0; t < 3; t++) {
        int j = jy0 + t;
        float w = fmaxf(1.f - fabsf(sy - (float)j) * 0.8f, 0.f);
        if (j < 0 || j > 319) w = 0.f;
        wy[t] = w; sumy += w;
    }
    const float isy = 1.f / sumy;
    const float sx = 2.5f * x + 0.75f;
    const int jx0 = (int)ceilf(sx - 2.5f);
    float wx[5]; float sumx = 0.f;
#pragma unroll
    for (int t = 0; t < 5; t++) {
        int j = jx0 + t;
        float w = fmaxf(1.f - fabsf(sx - (float)j) * 0.4f, 0.f);
        if (j < 0 || j > 639) w = 0.f;
        wx[t] = w; sumx += w;
    }
    const float isx = 1.f / sumx;

    float acc[16];
#pragma unroll
    for (int c = 0; c < 16; c++) acc[c] = 0.f;
#pragma unroll
    for (int a = 0; a < 3; a++) {
        const float wya = wy[a] * isy;
        if (wya <= 0.f) continue;
        const int prow = (jy0 + a) - jy_base;
#pragma unroll
        for (int b = 0; b < 5; b++) {
            const float wr = wya * wx[b] * isx;
            if (wr <= 0.f) continue;
            const int pos = prow * NXP + (jx0 + b) - jx_base;
#pragma unroll
            for (int qq = 0; qq < 2; qq++) {
                uint4 v = smp4[(half * 2 + qq) * NPOS + pos];
                float2 p0 = bfp(v.x), p1 = bfp(v.y), p2 = bfp(v.z), p3 = bfp(v.w);
                acc[8*qq+0] += wr * p0.x; acc[8*qq+1] += wr * p0.y;
                acc[8*qq+2] += wr * p1.x; acc[8*qq+3] += wr * p1.y;
                acc[8*qq+4] += wr * p2.x; acc[8*qq+5] += wr * p2.y;
                acc[8*qq+6] += wr * p3.x; acc[8*qq+7] += wr * p3.y;
            }
        }
    }
    uint4* d4 = (uint4*)(costs + (((size_t)(d * 256 + y) * 256 + x) * 128) + cam * 32 + half * 16);
#pragma unroll
    for (int qq = 0; qq < 2; qq++) {
        uint4 v;
        v.x = pk2(acc[8*qq+0], acc[8*qq+1]);
        v.y = pk2(acc[8*qq+2], acc[8*qq+3]);
        v.z = pk2(acc[8*qq+4], acc[8*qq+5]);
        v.w = pk2(acc[8*qq+6], acc[8*qq+7]);
        d4[qq] = v;
    }
}

// stage one (c, dd) input slice window (4 rows x 66 px x 64ci) into an LDS
// buffer via global_load_lds dwordx4. Slot j -> (yy, xl, g2); channel-group
// g = g2 ^ (xl&7) (involution applied identically on the read side).
// Border slots read the zero page (pad-0 conv).
template<int CI>
__device__ __forceinline__ void conv_stage(const ushort_t* __restrict__ in,
        const ushort_t* __restrict__ zp, ushort_t* ldst,
        int tid, int x0, int y0, int dd, int c) {
    constexpr int XL  = 66;
    constexpr int NIT = 4 * XL * 8;
    for (int j = tid; j < NIT; j += 256) {
        const int g2 = j & 7;
        const int xl = (j >> 3) % XL;
        const int yy = (j >> 3) / XL;
        const int g  = g2 ^ (xl & 7);
        const int gy = y0 - 1 + yy;
        const int gx = x0 - 1 + xl;
        const ushort_t* gsrc = ((unsigned)gy < 256u && (unsigned)gx < 256u)
            ? in + (((size_t)dd * 256 + gy) * 256 + gx) * CI + c * 64 + g * 8
            : zp;
        __builtin_amdgcn_global_load_lds(
            (const __attribute__((address_space(1))) unsigned int*)gsrc,
            (__attribute__((address_space(3))) unsigned int*)&ldst[j * 8],
            16, 0, 0);
    }
}

// MFMA implicit-GEMM conv3d (3x3x3, pad1) channels-last bf16, relu.
// 2-PHASE DOUBLE-BUFFERED (T3-minimum): while computing round rr from
// buffer cur, round rr+1's global_load_lds DMA is already in flight into
// buffer cur^1; the single __syncthreads per round drains it AFTER the
// ~1100-cyc MFMA block, hiding the staging latency that the previous
// serial-round structure (barrier-DMA-barrier-compute) exposed each round.
// Rounds flattened over (c, ddi); invalid-dd rounds skip stage+compute
// (block-uniform) and cost one barrier.
// Tile: 64 px x 2 rows (R3-proven); 4 waves = 2 x-halves x 2 y-rows; each
// wave 32 px x CO x DG. acc = DG*WN*16 = 32 VGPRs.
// LDS: 2 x 33,792 B = 67,584 -> 2 blocks/CU (launch_bounds(256,2)).
template<int CI, int CO, int DG>
__global__ __launch_bounds__(256, 2) void omni_conv3d_mfma(
        const ushort_t* __restrict__ in,
        const ushort_t* __restrict__ wb,
        const ushort_t* __restrict__ zp,
        ushort_t* __restrict__ out) {
    constexpr int WN  = CO / 32;        // 2 (fusion) / 1 (reg1)
    constexpr int XL  = 66;
    constexpr int NIT = 4 * XL * 8;     // 2112 slots of 16B per buffer
    constexpr int NR  = (CI / 64) * (DG + 2);   // flattened rounds
    __shared__ ushort_t lds[2 * NIT * 8];       // 67,584 B
    const int tid = threadIdx.x;
    const int lane = tid & 63;
    const int wid = tid >> 6;
    const int wx = wid & 1;             // x-half
    const int wy = wid >> 1;            // y-row
    const int x0 = blockIdx.x * 64;
    const int y0 = blockIdx.y * 2;
    const int d0 = blockIdx.z * DG;
    const int col = wx * 32 + (lane & 31);
    const int gc  = lane >> 5;          // k half

    f32x16 acc[DG][WN];
#pragma unroll
    for (int od = 0; od < DG; ++od)
#pragma unroll
        for (int nr = 0; nr < WN; ++nr)
#pragma unroll
            for (int r = 0; r < 16; ++r) acc[od][nr][r] = 0.f;

    // prologue: stage round 0 (c=0, ddi=0 -> dd = d0-1) if valid
    if (d0 - 1 >= 0)
        conv_stage<CI>(in, zp, lds, tid, x0, y0, d0 - 1, 0);
    __syncthreads();

#pragma unroll
    for (int rr = 0; rr < NR; ++rr) {
        const int cur = rr & 1;
        const int c   = rr / (DG + 2);
        const int ddi = rr % (DG + 2);
        const int dd  = d0 - 1 + ddi;
        // issue next round's staging into the other buffer (overlaps compute)
        if (rr + 1 < NR) {
            const int cn  = (rr + 1) / (DG + 2);
            const int ddn = d0 - 1 + (rr + 1) % (DG + 2);
            if (ddn >= 0 && ddn <= 3)
                conv_stage<CI>(in, zp, lds + (cur ^ 1) * (NIT * 8), tid, x0, y0, ddn, cn);
        }
        if (dd >= 0 && dd <= 3) {                  // block-uniform
            const ushort_t* lsrc = lds + cur * (NIT * 8);
            const ushort_t* wq = wb + (size_t)(c * 3) * (36 * WN * 512) + lane * 8;
#pragma unroll
            for (int ky = 0; ky < 3; ++ky) {
                const int arow = ky + wy;          // staged row 0..3
#pragma unroll
                for (int kx = 0; kx < 3; ++kx) {
                    const int xl = col + kx;
                    const int xs = xl & 7;
                    const int f0 = (ky * 3 + kx) * 4;
#pragma unroll
                    for (int ks = 0; ks < 4; ++ks) {
                        const int g = (ks * 2 + gc) ^ xs;
                        const bfrag a = *(const bfrag*)&lsrc[(((arow * XL + xl) << 3) + g) * 8];
#pragma unroll
                        for (int od = 0; od < DG; ++od) {
                            const int kd = ddi - od;   // compile-time (rr unrolled)
                            if (kd < 0 || kd > 2) continue;
#pragma unroll
                            for (int nr = 0; nr < WN; ++nr) {
                                const bfrag b = *(const bfrag*)(wq +
                                    (size_t)((kd * 36 + f0 + ks) * WN + nr) * 512);
                                acc[od][nr] = __builtin_amdgcn_mfma_f32_32x32x16_bf16(a, b, acc[od][nr], 0, 0, 0);
                            }
                        }
                    }
                }
            }
        }
        __syncthreads();                           // drains next-round DMA (overlapped)
    }
    // epilogue: relu + bf16 store. C/D: col=lane&31, row=(r&3)+8*(r>>2)+4*(lane>>5)
    const int yo = y0 + wy;
#pragma unroll
    for (int od = 0; od < DG; ++od) {
        const int dout = d0 + od;
#pragma unroll
        for (int nr = 0; nr < WN; ++nr) {
#pragma unroll
            for (int r = 0; r < 16; ++r) {
                const int row = (r & 3) + 8 * (r >> 2) + 4 * gc;
                const int px  = x0 + wx * 32 + row;
                const int co  = nr * 32 + (lane & 31);
                out[((size_t)(dout * 256 + yo) * 256 + px) * CO + co] = f2bf(fmaxf(acc[od][nr][r], 0.f));
            }
        }
    }
}

// Fused conv3d 32->1 + depth resize 4->8 + softmax + expectation.
// dd-split: block = 64 px x 4 dd-parts; parts 1-3 drop partials in LDS;
// part 0 combines + softmax + expectation.
__global__ __launch_bounds__(256) void omni_reg2disp(
        const ushort_t* __restrict__ in, const float* __restrict__ wt2,
        float* __restrict__ out) {
    __shared__ float wl[27 * 32];
    __shared__ float part[3][64][4];
    int tid = threadIdx.x;
    for (int i = tid; i < 864; i += 256) wl[i] = wt2[i];
    __syncthreads();
    const int l  = tid & 63;
    const int dd = tid >> 6;                        // 0..3: input slice
    const int px = blockIdx.x * 64 + l;             // 65536 px total
    const int x = px & 255;
    const int y = px >> 8;
    float acc[4] = {0.f, 0.f, 0.f, 0.f};
    for (int ky = 0; ky < 3; ky++) {
        int yy = y + ky - 1; if (yy < 0 || yy > 255) continue;
        for (int kx = 0; kx < 3; kx++) {
            int xx = x + kx - 1; if (xx < 0 || xx > 255) continue;
            const uint4* f4 = (const uint4*)(in + (((size_t)dd * 256 + yy) * 256 + xx) * 32);
            float vch[32];
#pragma unroll
            for (int q = 0; q < 4; q++) {
                uint4 v = f4[q];
                float2 p0 = bfp(v.x), p1 = bfp(v.y), p2 = bfp(v.z), p3 = bfp(v.w);
                vch[8*q+0] = p0.x; vch[8*q+1] = p0.y;
                vch[8*q+2] = p1.x; vch[8*q+3] = p1.y;
                vch[8*q+4] = p2.x; vch[8*q+5] = p2.y;
                vch[8*q+6] = p3.x; vch[8*q+7] = p3.y;
            }
#pragma unroll
            for (int kd = 0; kd < 3; kd++) {
                const int d = dd + 1 - kd;          // dd = d + kd - 1
                if (d < 0 || d > 3) continue;
                const float* wp = &wl[((kd * 3 + ky) * 3 + kx) * 32];
                float s = 0.f;
#pragma unroll
                for (int ch = 0; ch < 32; ch++) s += vch[ch] * wp[ch];
                acc[d] += s;
            }
        }
    }
    if (dd > 0) {
#pragma unroll
        for (int i = 0; i < 4; i++) part[dd - 1][l][i] = acc[i];
    }
    __syncthreads();
    if (dd != 0) return;
#pragma unroll
    for (int p = 0; p < 3; p++)
#pragma unroll
        for (int i = 0; i < 4; i++) acc[i] += part[p][l][i];
    // depth resize 4->8 + softmax + expectation
    float lv[8];
    lv[0] = acc[0];
    lv[1] = 0.75f * acc[0] + 0.25f * acc[1];
    lv[2] = 0.25f * acc[0] + 0.75f * acc[1];
    lv[3] = 0.75f * acc[1] + 0.25f * acc[2];
    lv[4] = 0.25f * acc[1] + 0.75f * acc[2];
    lv[5] = 0.75f * acc[2] + 0.25f * acc[3];
    lv[6] = 0.25f * acc[2] + 0.75f * acc[3];
    lv[7] = acc[3];
    float m = lv[0];
#pragma unroll
    for (int i = 1; i < 8; i++) m = fmaxf(m, lv[i]);
    float s = 0.f, e = 0.f;
#pragma unroll
    for (int i = 0; i < 8; i++) {
        float p = expf(lv[i] - m);
        s += p; e += p * (float)i;
    }
    out[px] = e / s;
}

extern "C" void kernel_launch(void* const* d_in, const int* in_sizes, int n_in,
                              void* d_out, int out_size, void* d_ws, size_t ws_size,
                              hipStream_t stream) {
    const float* cam0 = (const float*)d_in[0];
    const float* cam1 = (const float*)d_in[1];
    const float* cam2 = (const float*)d_in[2];
    const float* cam3 = (const float*)d_in[3];
    const float* grids = (const float*)d_in[4];
    const float* w_feat = (const float*)d_in[5];
    const float* w_fusion = (const float*)d_in[6];
    const float* w_reg1 = (const float*)d_in[7];
    const float* w_reg2 = (const float*)d_in[8];

    char* base = (char*)d_ws;
    ushort_t* feat  = (ushort_t*)(base);
    ushort_t* costs = (ushort_t*)(base + 52428800);
    ushort_t* x1    = (ushort_t*)(base + 119537664);
    ushort_t* x2    = (ushort_t*)(base + 153092096);
    ushort_t* wbf   = (ushort_t*)(base + 170917888);
    ushort_t* wb1   = (ushort_t*)(base + 171360256);
    float*    wt2   = (float*)   (base + 171470848);
    ushort_t* zp    = (ushort_t*)(base + 171474304);   // 64-B zero page

    omni_prep<<<1084, 256, 0, stream>>>(w_fusion, w_reg1, w_reg2, wbf, wb1, wt2, (float*)zp);

    omni_feat_conv<<<3200, 256, 0, stream>>>(cam0, cam1, cam2, cam3, w_feat, feat);
    omni_warp_resize<<<8192, 256, 0, stream>>>(feat, grids, costs);
    omni_conv3d_mfma<128, 64, 1><<<dim3(4, 128, 4), 256, 0, stream>>>(costs, wbf, zp, x1);
    omni_conv3d_mfma<64, 32, 2><<<dim3(4, 128, 2), 256, 0, stream>>>(x1, wb1, zp, x2);
    omni_reg2disp<<<1024, 256, 0, stream>>>(x2, wt2, (float*)d_out);
}

// Round 13
// 486.309 us; speedup vs baseline: 1.0627x; 1.0627x over previous
//
#include <hip/hip_runtime.h>

typedef __attribute__((ext_vector_type(8))) __bf16 bfrag;
typedef __attribute__((ext_vector_type(16))) float f32x16;
typedef unsigned short ushort_t;

__device__ __forceinline__ unsigned short f2bf(float f) {
    union { unsigned int u; float f; } c; c.f = f;
    unsigned int u = c.u;
    return (unsigned short)((u + 0x7FFFu + ((u >> 16) & 1u)) >> 16);
}
__device__ __forceinline__ float2 bfp(unsigned int u) {
    union { unsigned int u; float f; } lo, hi;
    lo.u = u << 16; hi.u = u & 0xFFFF0000u;
    return make_float2(lo.f, hi.f);
}
__device__ __forceinline__ unsigned int pk2(float a, float b) {
    return ((unsigned)f2bf(b) << 16) | f2bf(a);
}

// ---------------- workspace layout (bytes) ----------------
// feat  bf16 [4][320][640][32]   at 0          (52,428,800)
// costs bf16 [4][256][256][128]  at 52428800   (67,108,864)
// x1    bf16 [4][256][256][64]   at 119537664  (33,554,432)
// x2    bf16 [4][256][256][32]   at 153092096  (16,777,216)
// wbf   bf16 packed fusion       at 170917888  (442,368)
// wb1   bf16 packed reg1         at 171360256  (110,592)
// wt2   f32  [kpos][32]          at 171470848  (3,456)
// zp    zero page (64 B)         at 171474304  (64)
//
// SESSION STATE (R12): this is the R9/R11-verified optimum (487.9 us,
// reproduced twice). Measured dead ends — do not re-attempt:
//  - warp_resize: branchless-clamp (R5 194us), tap-batching (R6/R7 spill,
//    WRITE 221MB), 16x4/8-blk TLP (R8 233us). Gather-throughput bound.
//  - conv3d: DG=2 fusion (R2 +30us), M64/YB4 (R4 neutral), 2-phase dbuf
//    (R12 +29us: 3->2 blocks/CU occupancy loss > latency hidden, m132
//    precedent). Serial-round @ 3 blocks/CU is the plain-HIP optimum.
//  - feat_conv: LDS-tiled variant (R10: 156 VGPR, 11% occ, 235us).

// pack conv3d weights (OIDHW fp32) into MFMA B-fragment order, bf16.
// layout: [p = c*3+kd][f = tap*4+ks][wn][lane][8]
template<int CI, int CO>
__device__ __forceinline__ void pack_w_elem(const float* __restrict__ w,
                                            ushort_t* __restrict__ dst, int o) {
    constexpr int WN = CO / 32;
    const int j = o & 7;
    const int lane = (o >> 3) & 63;
    int r = o >> 9;
    const int wn = r % WN; r /= WN;
    const int f = r % 36;  const int p = r / 36;
    const int tap = f >> 2, ks = f & 3;
    const int c = p / 3, kd = p % 3;
    const int co = wn * 32 + (lane & 31);
    const int ci = c * 64 + ks * 16 + (lane >> 5) * 8 + j;
    const int ky = tap / 3, kx = tap % 3;
    dst[o] = f2bf(w[(((size_t)(co * CI + ci) * 3 + kd) * 3 + ky) * 3 + kx]);
}

// single merged weight-prep kernel: fusion pack (864 blocks), reg1 pack
// (216 blocks), reg2 transpose + zero-page (4 blocks). Saves 2 launch gaps.
__global__ void omni_prep(const float* __restrict__ w_fusion,
                          const float* __restrict__ w_reg1,
                          const float* __restrict__ w_reg2,
                          ushort_t* __restrict__ wbf, ushort_t* __restrict__ wb1,
                          float* __restrict__ wt2, float* __restrict__ zp) {
    const int b = blockIdx.x;
    const int tid = threadIdx.x;
    if (b < 864) {
        pack_w_elem<128, 64>(w_fusion, wbf, b * 256 + tid);      // n = 221184 exact
    } else if (b < 1080) {
        pack_w_elem<64, 32>(w_reg1, wb1, (b - 864) * 256 + tid); // n = 55296 exact
    } else {
        const int i = (b - 1080) * 256 + tid;                    // 0..1023
        if (i >= 864) {
            if (i - 864 < 16) zp[i - 864] = 0.f;
            return;
        }
        const int ci = i % 32;
        const int kpos = i / 32;
        wt2[i] = w_reg2[ci * 27 + kpos];
    }
}

// conv2d stride2 pad1 + relu; input NCHW [3,640,1280]; out bf16 channels-last
// [cam][320][640][32]. Simple 27-scalar-load form compiles lean (44 VGPR,
// latency hidden by occupancy) — proven config.
__global__ __launch_bounds__(256) void omni_feat_conv(
        const float* __restrict__ c0, const float* __restrict__ c1,
        const float* __restrict__ c2, const float* __restrict__ c3,
        const float* __restrict__ w, ushort_t* __restrict__ feat) {
    __shared__ float wl[864];
    int tid = threadIdx.x;
    for (int i = tid; i < 864; i += 256) wl[i] = w[i];
    __syncthreads();
    int gid = blockIdx.x * 256 + tid;               // 4*320*640
    int ox = gid % 640;
    int t = gid / 640;
    int oy = t % 320;
    int cam = t / 320;
    const float* src = (cam == 0) ? c0 : (cam == 1) ? c1 : (cam == 2) ? c2 : c3;
    float acc[32];
#pragma unroll
    for (int i = 0; i < 32; i++) acc[i] = 0.f;
    for (int ky = 0; ky < 3; ky++) {
        int iy = oy * 2 - 1 + ky;
        if (iy < 0 || iy >= 640) continue;
        for (int kx = 0; kx < 3; kx++) {
            int ix = ox * 2 - 1 + kx;
            if (ix < 0 || ix >= 1280) continue;
#pragma unroll
            for (int ci = 0; ci < 3; ci++) {
                float v = src[(ci * 640 + iy) * 1280 + ix];
#pragma unroll
                for (int co = 0; co < 32; co++)
                    acc[co] += v * wl[((co * 3 + ci) * 3 + ky) * 3 + kx];
            }
        }
    }
    uint4* d4 = (uint4*)(feat + (size_t)gid * 32);
#pragma unroll
    for (int q = 0; q < 4; q++) {
        uint4 v;
        v.x = pk2(fmaxf(acc[8*q+0],0.f), fmaxf(acc[8*q+1],0.f));
        v.y = pk2(fmaxf(acc[8*q+2],0.f), fmaxf(acc[8*q+3],0.f));
        v.z = pk2(fmaxf(acc[8*q+4],0.f), fmaxf(acc[8*q+5],0.f));
        v.w = pk2(fmaxf(acc[8*q+6],0.f), fmaxf(acc[8*q+7],0.f));
        d4[q] = v;
    }
}

// Tiled fused grid_sample + antialiased resize — R4-proven configuration.
// L2-miss-gather-throughput bound; empirical best operating point:
// 16x8 tile, 5 blocks/CU, branchy taps (44 VGPR, no spill), XCD-chunked
// swizzle.
#define NXP 42
#define NYP 12
#define NPOS (NXP * NYP)   // 504
__global__ __launch_bounds__(256, 5) void omni_warp_resize(
        const ushort_t* __restrict__ feat, const float* __restrict__ grids,
        ushort_t* __restrict__ costs) {
    __shared__ uint4 smp4[4 * NPOS];   // 32,256 B -> 5 blocks/CU
    const int tid = threadIdx.x;
    const int bid0 = blockIdx.x;
    const int bid = (bid0 & 7) * 1024 + (bid0 >> 3);   // bijective: XCD k <- chunk k
    const int tx  = bid & 15;
    const int ty  = (bid >> 4) & 31;
    const int d   = (bid >> 9) & 3;
    const int cam = bid >> 11;
    const int x0 = tx * 16, y0 = ty * 8;
    const int jx_base = 40 * tx - 1;
    const int jy_base = 10 * ty - 1;
    const float* gbase = grids + ((size_t)(cam * 4 + d) * 320) * 640 * 2;
    const ushort_t* fbase = feat + (size_t)cam * 320 * 640 * 32;

    for (int i = tid; i < NPOS; i += 256) {
        const int jy = jy_base + i / NXP;
        const int jx = jx_base + i % NXP;
        float acc[32];
#pragma unroll
        for (int c = 0; c < 32; c++) acc[c] = 0.f;
        if ((unsigned)jy < 320u && (unsigned)jx < 640u) {
            const float gx = gbase[((size_t)jy * 640 + jx) * 2];
            const float gy = gbase[((size_t)jy * 640 + jx) * 2 + 1];
            const float fx = (gx + 1.f) * 320.f - 0.5f;
            const float fy = (gy + 1.f) * 160.f - 0.5f;
            const float x0f = floorf(fx), y0f = floorf(fy);
            const float ax = fx - x0f, ay = fy - y0f;
            const int sx0 = (int)x0f, sy0 = (int)y0f;
            const float tw[4] = {(1.f-ax)*(1.f-ay), ax*(1.f-ay), (1.f-ax)*ay, ax*ay};
            const int xs4[4] = {sx0, sx0+1, sx0, sx0+1};
            const int ys4[4] = {sy0, sy0, sy0+1, sy0+1};
#pragma unroll
            for (int tc = 0; tc < 4; tc++) {
                const int xi = xs4[tc], yi = ys4[tc];
                if (xi < 0 || xi >= 640 || yi < 0 || yi >= 320) continue;
                const float wt = tw[tc];
                const uint4* f4 = (const uint4*)(fbase + ((size_t)yi * 640 + xi) * 32);
#pragma unroll
                for (int q = 0; q < 4; q++) {
                    uint4 v = f4[q];
                    float2 p0 = bfp(v.x), p1 = bfp(v.y), p2 = bfp(v.z), p3 = bfp(v.w);
                    acc[8*q+0] += wt * p0.x; acc[8*q+1] += wt * p0.y;
                    acc[8*q+2] += wt * p1.x; acc[8*q+3] += wt * p1.y;
                    acc[8*q+4] += wt * p2.x; acc[8*q+5] += wt * p2.y;
                    acc[8*q+6] += wt * p3.x; acc[8*q+7] += wt * p3.y;
                }
            }
        }
#pragma unroll
        for (int q = 0; q < 4; q++) {
            uint4 v;
            v.x = pk2(acc[8*q+0], acc[8*q+1]);
            v.y = pk2(acc[8*q+2], acc[8*q+3]);
            v.z = pk2(acc[8*q+4], acc[8*q+5]);
            v.w = pk2(acc[8*q+6], acc[8*q+7]);
            smp4[q * NPOS + i] = v;
        }
    }
    __syncthreads();

    const int half = tid >> 7;
    const int p = tid & 127;
    const int x = x0 + (p & 15);
    const int y = y0 + (p >> 4);

    const float sy = 1.25f * y + 0.125f;
    const int jy0 = (int)ceilf(sy - 1.25f);
    float wy[3]; float sumy = 0.f;
#pragma unroll
    for (int t = 0; t < 3; t++) {
        int j = jy0 + t;
        float w = fmaxf(1.f - fabsf(sy - (float)j) * 0.8f, 0.f);
        if (j < 0 || j > 319) w = 0.f;
        wy[t] = w; sumy += w;
    }
    const float isy = 1.f / sumy;
    const float sx = 2.5f * x + 0.75f;
    const int jx0 = (int)ceilf(sx - 2.5f);
    float wx[5]; float sumx = 0.f;
#pragma unroll
    for (int t = 0; t < 5; t++) {
        int j = jx0 + t;
        float w = fmaxf(1.f - fabsf(sx - (float)j) * 0.4f, 0.f);
        if (j < 0 || j > 639) w = 0.f;
        wx[t] = w; sumx += w;
    }
    const float isx = 1.f / sumx;

    float acc[16];
#pragma unroll
    for (int c = 0; c < 16; c++) acc[c] = 0.f;
#pragma unroll
    for (int a = 0; a < 3; a++) {
        const float wya = wy[a] * isy;
        if (wya <= 0.f) continue;
        const int prow = (jy0 + a) - jy_base;
#pragma unroll
        for (int b = 0; b < 5; b++) {
            const float wr = wya * wx[b] * isx;
            if (wr <= 0.f) continue;
            const int pos = prow * NXP + (jx0 + b) - jx_base;
#pragma unroll
            for (int qq = 0; qq < 2; qq++) {
                uint4 v = smp4[(half * 2 + qq) * NPOS + pos];
                float2 p0 = bfp(v.x), p1 = bfp(v.y), p2 = bfp(v.z), p3 = bfp(v.w);
                acc[8*qq+0] += wr * p0.x; acc[8*qq+1] += wr * p0.y;
                acc[8*qq+2] += wr * p1.x; acc[8*qq+3] += wr * p1.y;
                acc[8*qq+4] += wr * p2.x; acc[8*qq+5] += wr * p2.y;
                acc[8*qq+6] += wr * p3.x; acc[8*qq+7] += wr * p3.y;
            }
        }
    }
    uint4* d4 = (uint4*)(costs + (((size_t)(d * 256 + y) * 256 + x) * 128) + cam * 32 + half * 16);
#pragma unroll
    for (int qq = 0; qq < 2; qq++) {
        uint4 v;
        v.x = pk2(acc[8*qq+0], acc[8*qq+1]);
        v.y = pk2(acc[8*qq+2], acc[8*qq+3]);
        v.z = pk2(acc[8*qq+4], acc[8*qq+5]);
        v.w = pk2(acc[8*qq+6], acc[8*qq+7]);
        d4[qq] = v;
    }
}

// MFMA implicit-GEMM conv3d (3x3x3, pad1) channels-last bf16, relu.
// Tile: 64 px x YB=4 output rows x DG depths. 4 waves = 4 y-rows; each wave
// computes its FULL 64-px row via TWO A-fragments (mx=0,1) sharing every
// B-fragment -> B:MFMA = 1:2, A ds_read:MFMA halved. Serial-round 2-barrier
// structure @ 3 blocks/CU — measured optimum (R12: dbuf @ 2 blocks/CU +29us).
// A window (6 rows x 66 px x 64ci) staged via global_load_lds dwordx4.
// LDS LINEAR in slot order [row][xl][g]; slot index g XOR-swizzled with
// (xl&7) on BOTH the global source address and the ds_read_b128 address
// (involution) -> 2-way banks (free). OOB halo lanes read a zeroed
// 64-B page (pad-0 conv), keeping DMA full-wave uniform.
template<int CI, int CO, int DG>
__global__ __launch_bounds__(256, 3) void omni_conv3d_mfma(
        const ushort_t* __restrict__ in,
        const ushort_t* __restrict__ wb,
        const ushort_t* __restrict__ zp,
        ushort_t* __restrict__ out) {
    constexpr int WN   = CO / 32;       // 2 (fusion) / 1 (reg1)
    constexpr int XL   = 66;
    constexpr int NROW = 6;             // 4 output rows + 2 halo
    constexpr int NIT  = NROW * XL * 8; // 3168 slots of 16B
    __shared__ ushort_t lds[NIT * 8];   // 50,688 B -> 3 blocks/CU
    const int tid = threadIdx.x;
    const int lane = tid & 63;
    const int wy  = tid >> 6;           // wave = output row 0..3
    const int x0 = blockIdx.x * 64;
    const int y0 = blockIdx.y * 4;
    const int d0 = blockIdx.z * DG;
    const int colb = lane & 31;
    const int gc   = lane >> 5;         // k half

    f32x16 acc[DG][2][WN];
#pragma unroll
    for (int od = 0; od < DG; ++od)
#pragma unroll
        for (int mx = 0; mx < 2; ++mx)
#pragma unroll
            for (int nr = 0; nr < WN; ++nr)
#pragma unroll
                for (int r = 0; r < 16; ++r) acc[od][mx][nr][r] = 0.f;

    for (int c = 0; c < CI / 64; ++c) {
        // per-c weight base for kd=0 (p = c*3): kd offsets below
        const ushort_t* wq = wb + (size_t)(c * 3) * (36 * WN * 512) + lane * 8;
#pragma unroll
        for (int ddi = 0; ddi < DG + 2; ++ddi) {
            const int dd = d0 - 1 + ddi;               // input depth slice
            if (dd < 0 || dd > 3) continue;            // block-uniform
            __syncthreads();
            // stage 6 rows x 66 px x 64ci of slice dd directly to LDS.
            // slot j -> (yy, xl, g2); data channel-group g = g2 ^ (xl&7).
            for (int j = tid; j < NIT; j += 256) {
                const int g2 = j & 7;
                const int xl = (j >> 3) % XL;
                const int yy = (j >> 3) / XL;
                const int g  = g2 ^ (xl & 7);
                const int gy = y0 - 1 + yy;
                const int gx = x0 - 1 + xl;
                const ushort_t* gsrc = ((unsigned)gy < 256u && (unsigned)gx < 256u)
                    ? in + (((size_t)dd * 256 + gy) * 256 + gx) * CI + c * 64 + g * 8
                    : zp;
                __builtin_amdgcn_global_load_lds(
                    (const __attribute__((address_space(1))) unsigned int*)gsrc,
                    (__attribute__((address_space(3))) unsigned int*)&lds[j * 8],
                    16, 0, 0);
            }
            __syncthreads();                           // drains vmcnt
#pragma unroll
            for (int ky = 0; ky < 3; ++ky) {
                const int arow = ky + wy;              // staged row 0..5
#pragma unroll
                for (int kx = 0; kx < 3; ++kx) {
                    const int xl0 = colb + kx;
                    const int xs  = xl0 & 7;
                    const int f0  = (ky * 3 + kx) * 4;
#pragma unroll
                    for (int ks = 0; ks < 4; ++ks) {
                        const int g = (ks * 2 + gc) ^ xs;
                        const bfrag a0 = *(const bfrag*)&lds[(((arow * XL + xl0) << 3) + g) * 8];
                        const bfrag a1 = *(const bfrag*)&lds[(((arow * XL + xl0 + 32) << 3) + g) * 8];
#pragma unroll
                        for (int od = 0; od < DG; ++od) {
                            const int kd = ddi - od;
                            if (kd < 0 || kd > 2) continue;
#pragma unroll
                            for (int nr = 0; nr < WN; ++nr) {
                                const bfrag b = *(const bfrag*)(wq +
                                    (size_t)((kd * 36 + f0 + ks) * WN + nr) * 512);
                                acc[od][0][nr] = __builtin_amdgcn_mfma_f32_32x32x16_bf16(a0, b, acc[od][0][nr], 0, 0, 0);
                                acc[od][1][nr] = __builtin_amdgcn_mfma_f32_32x32x16_bf16(a1, b, acc[od][1][nr], 0, 0, 0);
                            }
                        }
                    }
                }
            }
        }
    }
    // epilogue: relu + bf16 store. C/D: col=lane&31, row=(r&3)+8*(r>>2)+4*(lane>>5)
    const int yo = y0 + wy;
#pragma unroll
    for (int od = 0; od < DG; ++od) {
        const int dout = d0 + od;
#pragma unroll
        for (int mx = 0; mx < 2; ++mx) {
#pragma unroll
            for (int nr = 0; nr < WN; ++nr) {
#pragma unroll
                for (int r = 0; r < 16; ++r) {
                    const int row = (r & 3) + 8 * (r >> 2) + 4 * gc;
                    const int px  = x0 + mx * 32 + row;
                    const int co  = nr * 32 + (lane & 31);
                    out[((size_t)(dout * 256 + yo) * 256 + px) * CO + co] = f2bf(fmaxf(acc[od][mx][nr][r], 0.f));
                }
            }
        }
    }
}

// Fused conv3d 32->1 + depth resize 4->8 + softmax + expectation.
// dd-split: block = 64 px x 4 dd-parts; parts 1-3 drop partials in LDS;
// part 0 combines + softmax + expectation.
__global__ __launch_bounds__(256) void omni_reg2disp(
        const ushort_t* __restrict__ in, const float* __restrict__ wt2,
        float* __restrict__ out) {
    __shared__ float wl[27 * 32];
    __shared__ float part[3][64][4];
    int tid = threadIdx.x;
    for (int i = tid; i < 864; i += 256) wl[i] = wt2[i];
    __syncthreads();
    const int l  = tid & 63;
    const int dd = tid >> 6;                        // 0..3: input slice
    const int px = blockIdx.x * 64 + l;             // 65536 px total
    const int x = px & 255;
    const int y = px >> 8;
    float acc[4] = {0.f, 0.f, 0.f, 0.f};
    for (int ky = 0; ky < 3; ky++) {
        int yy = y + ky - 1; if (yy < 0 || yy > 255) continue;
        for (int kx = 0; kx < 3; kx++) {
            int xx = x + kx - 1; if (xx < 0 || xx > 255) continue;
            const uint4* f4 = (const uint4*)(in + (((size_t)dd * 256 + yy) * 256 + xx) * 32);
            float vch[32];
#pragma unroll
            for (int q = 0; q < 4; q++) {
                uint4 v = f4[q];
                float2 p0 = bfp(v.x), p1 = bfp(v.y), p2 = bfp(v.z), p3 = bfp(v.w);
                vch[8*q+0] = p0.x; vch[8*q+1] = p0.y;
                vch[8*q+2] = p1.x; vch[8*q+3] = p1.y;
                vch[8*q+4] = p2.x; vch[8*q+5] = p2.y;
                vch[8*q+6] = p3.x; vch[8*q+7] = p3.y;
            }
#pragma unroll
            for (int kd = 0; kd < 3; kd++) {
                const int d = dd + 1 - kd;          // dd = d + kd - 1
                if (d < 0 || d > 3) continue;
                const float* wp = &wl[((kd * 3 + ky) * 3 + kx) * 32];
                float s = 0.f;
#pragma unroll
                for (int ch = 0; ch < 32; ch++) s += vch[ch] * wp[ch];
                acc[d] += s;
            }
        }
    }
    if (dd > 0) {
#pragma unroll
        for (int i = 0; i < 4; i++) part[dd - 1][l][i] = acc[i];
    }
    __syncthreads();
    if (dd != 0) return;
#pragma unroll
    for (int p = 0; p < 3; p++)
#pragma unroll
        for (int i = 0; i < 4; i++) acc[i] += part[p][l][i];
    // depth resize 4->8 + softmax + expectation
    float lv[8];
    lv[0] = acc[0];
    lv[1] = 0.75f * acc[0] + 0.25f * acc[1];
    lv[2] = 0.25f * acc[0] + 0.75f * acc[1];
    lv[3] = 0.75f * acc[1] + 0.25f * acc[2];
    lv[4] = 0.25f * acc[1] + 0.75f * acc[2];
    lv[5] = 0.75f * acc[2] + 0.25f * acc[3];
    lv[6] = 0.25f * acc[2] + 0.75f * acc[3];
    lv[7] = acc[3];
    float m = lv[0];
#pragma unroll
    for (int i = 1; i < 8; i++) m = fmaxf(m, lv[i]);
    float s = 0.f, e = 0.f;
#pragma unroll
    for (int i = 0; i < 8; i++) {
        float p = expf(lv[i] - m);
        s += p; e += p * (float)i;
    }
    out[px] = e / s;
}

extern "C" void kernel_launch(void* const* d_in, const int* in_sizes, int n_in,
                              void* d_out, int out_size, void* d_ws, size_t ws_size,
                              hipStream_t stream) {
    const float* cam0 = (const float*)d_in[0];
    const float* cam1 = (const float*)d_in[1];
    const float* cam2 = (const float*)d_in[2];
    const float* cam3 = (const float*)d_in[3];
    const float* grids = (const float*)d_in[4];
    const float* w_feat = (const float*)d_in[5];
    const float* w_fusion = (const float*)d_in[6];
    const float* w_reg1 = (const float*)d_in[7];
    const float* w_reg2 = (const float*)d_in[8];

    char* base = (char*)d_ws;
    ushort_t* feat  = (ushort_t*)(base);
    ushort_t* costs = (ushort_t*)(base + 52428800);
    ushort_t* x1    = (ushort_t*)(base + 119537664);
    ushort_t* x2    = (ushort_t*)(base + 153092096);
    ushort_t* wbf   = (ushort_t*)(base + 170917888);
    ushort_t* wb1   = (ushort_t*)(base + 171360256);
    float*    wt2   = (float*)   (base + 171470848);
    ushort_t* zp    = (ushort_t*)(base + 171474304);   // 64-B zero page

    omni_prep<<<1084, 256, 0, stream>>>(w_fusion, w_reg1, w_reg2, wbf, wb1, wt2, (float*)zp);

    omni_feat_conv<<<3200, 256, 0, stream>>>(cam0, cam1, cam2, cam3, w_feat, feat);
    omni_warp_resize<<<8192, 256, 0, stream>>>(feat, grids, costs);
    omni_conv3d_mfma<128, 64, 1><<<dim3(4, 64, 4), 256, 0, stream>>>(costs, wbf, zp, x1);
    omni_conv3d_mfma<64, 32, 2><<<dim3(4, 64, 2), 256, 0, stream>>>(x1, wb1, zp, x2);
    omni_reg2disp<<<1024, 256, 0, stream>>>(x2, wt2, (float*)d_out);
}